// Round 7
// baseline (103.013 us; speedup 1.0000x reference)
//
#include <hip/hip_runtime.h>
#include <hip/hip_bf16.h>

// Problem constants
#define M_DIM 256     // B*T
#define K_DIM 8192
#define N_DIM 8192
#define NGRP  64      // N/128 groups

// Tile config
#define BN 128        // W rows per block (8 waves x 16 rows)
#define BK 32         // n per step
#define THREADS 512   // 8 waves, each owns a 16-row k-slice
#define SPLITN 8
#define CHUNK  (N_DIM / SPLITN)   // 1024
#define NSTEPS (CHUNK / BK)       // 32
#define NG     (CHUNK >> 7)       // 8 groups per chunk

// LDS: A triple-buffered (global_load_lds) + scales. B never touches LDS.
#define ASIZE 16384               // bf16 [256][32]
#define SL_OFF (3 * ASIZE)
#define LDS_TOTAL (SL_OFF + NG * 128 * 8)   // 48K + 8K = 56KB

typedef __bf16 bf16x8 __attribute__((ext_vector_type(8)));
typedef __bf16 bf16x4 __attribute__((ext_vector_type(4)));
typedef float  f32x4  __attribute__((ext_vector_type(4)));

// XOR swizzle for the A region (involution, 16B granules within 128B blocks)
#define SW(a) ((a) ^ ((((a) >> 7) & 7) << 4))

#define GLOAD_LDS16(g, l) __builtin_amdgcn_global_load_lds( \
    (const __attribute__((address_space(1))) void*)(g),     \
    (__attribute__((address_space(3))) void*)(l), 16, 0, 0)

// ---------------- Kernel 0: xs[m,n] = bf16(x[m,n] * mu1[n]) ----------------
__global__ __launch_bounds__(256) void prep_xs(const float* __restrict__ x,
                                               const float* __restrict__ mu1,
                                               __bf16* __restrict__ xs) {
    int t  = blockIdx.x * 256 + threadIdx.x;
    int n4 = t & 2047;
    int m  = t >> 11;
    int n  = n4 << 2;
    float4 xv = *(const float4*)(x + (size_t)m * N_DIM + n);
    float4 mv = *(const float4*)(mu1 + n);
    bf16x4 o;
    o[0] = (__bf16)(xv.x * mv.x);
    o[1] = (__bf16)(xv.y * mv.y);
    o[2] = (__bf16)(xv.z * mv.z);
    o[3] = (__bf16)(xv.w * mv.w);
    *(bf16x4*)(xs + (size_t)m * N_DIM + n) = o;
}

// ---------------- Kernel 1: B-direct-to-reg pipelined split-K GEMM ----------------
__global__ __launch_bounds__(THREADS, 4)
void gemm_q(const __bf16* __restrict__ xs, const int* __restrict__ Wq,
            const float* __restrict__ scales, const float* __restrict__ zeros,
            __bf16* __restrict__ partial) {
    extern __shared__ __align__(1024) char lds[];

    const int b     = blockIdx.x;      // 512 blocks
    const int split = b & 7;           // XCD-affine: one split per XCD
    const int kidx  = b >> 3;          // 0..63
    const int k0    = kidx * BN;
    const int nbase = split * CHUNK;
    const int gbase = split * NG;

    const int tid  = threadIdx.x;
    const int lane = tid & 63;
    const int w    = tid >> 6;               // k-slice 0..7 (16 W rows each)
    const int start = kidx & (NSTEPS - 1);   // n-rotation

    float* SL = (float*)(lds + SL_OFF);      // [NG][128] x {s, -z*s}

    // ---- stage scales/zeros (once) ----
    {
        int r = tid >> 2, gq = tid & 3;
#pragma unroll
        for (int gg = 0; gg < (NG >> 2); ++gg) {
            int g = (gg << 2) | gq;
            size_t si = (size_t)(k0 + r) * NGRP + gbase + g;
            float s = scales[si];
            float z = zeros[si];
            float2 v; v.x = s; v.y = -z * s;
            *(float2*)&SL[(size_t)((g << 7) + r) * 2] = v;
        }
    }

    // ---- A staging via global_load_lds: 2x 1KB chunks per wave ----
    const char* asrc[2];
    int aoff[2];
#pragma unroll
    for (int cc = 0; cc < 2; ++cc) {
        int c   = w * 2 + cc;            // 0..15
        int off = c * 1024 + lane * 16;  // linear LDS dest
        int L   = SW(off);               // logical element (inverse-swizzled src)
        aoff[cc] = off;
        asrc[cc] = (const char*)xs + ((size_t)(L >> 6) * N_DIM) * 2 + (L & 63);
    }

    // ---- B direct: lane reads 8 codes of its own row (contiguous 128B/row) ----
    // MFMA B-frag layout: lane&15 = row-within-16, (lane>>4)*8+j = n element.
    const int browL = w * 16 + (lane & 15);  // 0..127 (this lane's W row)
    const int* bptr0 = Wq + (size_t)(k0 + browL) * N_DIM + (lane >> 4) * 8;

#define ISSUE_A(t)                                                        \
    {                                                                     \
        int s_ = ((t) + start) & (NSTEPS - 1);                            \
        char* bs_ = lds + ((t) % 3) * ASIZE;                              \
        size_t so_ = (size_t)(nbase + s_ * BK) * 2;                       \
        GLOAD_LDS16(asrc[0] + so_, bs_ + aoff[0]);                        \
        GLOAD_LDS16(asrc[1] + so_, bs_ + aoff[1]);                        \
    }
#define LOAD_B(t, q0, q1)                                                 \
    {                                                                     \
        int s_ = ((t) + start) & (NSTEPS - 1);                            \
        const int* p_ = bptr0 + (nbase + s_ * BK);                        \
        q0 = *(const int4*)p_;                                            \
        q1 = *(const int4*)(p_ + 4);                                      \
    }

    f32x4 acc[16];
#pragma unroll
    for (int i = 0; i < 16; ++i)
        acc[i] = (f32x4){0.f, 0.f, 0.f, 0.f};

    int4 qa0, qa1, qb0, qb1;

    // prologue: step-0 group [B0(2),A0(2)], fence, step-1 group [B1,A1].
    // FIFO: vmcnt(4) at step t drains exactly group t.
    LOAD_B(0, qa0, qa1);
    ISSUE_A(0);
    asm volatile("" ::: "memory");
    LOAD_B(1, qb0, qb1);
    ISSUE_A(1);
    asm volatile("s_waitcnt lgkmcnt(0)" ::: "memory");  // SL ds_writes drained

    float sc = 0.f, zs = 0.f;

    // STEP: wait+barrier | dequant B(it) regs->bv | issue group(it+2) | frags+MFMA
#define STEP(it, q0c, q1c)                                                \
    {                                                                     \
        if ((it) < NSTEPS - 1) asm volatile("s_waitcnt vmcnt(4)" ::: "memory"); \
        else                   asm volatile("s_waitcnt vmcnt(0)" ::: "memory"); \
        __builtin_amdgcn_s_barrier();  /* A(it) staged by all waves */    \
        int scur_ = ((it) + start) & (NSTEPS - 1);                        \
        if ((scur_ & 3) == 0 || (it) == 0) {                              \
            float2 v_ = *(float2*)&SL[(size_t)(((scur_ >> 2) << 7) + browL) * 2]; \
            sc = v_.x; zs = v_.y;                                         \
        }                                                                 \
        bf16x8 bv_;                                                       \
        bv_[0] = (__bf16)((float)q0c.x * sc + zs);                        \
        bv_[1] = (__bf16)((float)q0c.y * sc + zs);                        \
        bv_[2] = (__bf16)((float)q0c.z * sc + zs);                        \
        bv_[3] = (__bf16)((float)q0c.w * sc + zs);                        \
        bv_[4] = (__bf16)((float)q1c.x * sc + zs);                        \
        bv_[5] = (__bf16)((float)q1c.y * sc + zs);                        \
        bv_[6] = (__bf16)((float)q1c.z * sc + zs);                        \
        bv_[7] = (__bf16)((float)q1c.w * sc + zs);                        \
        if ((it) + 2 < NSTEPS) {                                          \
            LOAD_B((it) + 2, q0c, q1c);                                   \
            ISSUE_A((it) + 2);                                            \
        }                                                                 \
        const char* bufA_ = lds + ((it) % 3) * ASIZE;                     \
        _Pragma("unroll")                                                 \
        for (int mi = 0; mi < 16; ++mi) {                                 \
            int la_ = (mi * 16 + (lane & 15)) * 64 + (lane >> 4) * 16;    \
            bf16x8 av_ = *(const bf16x8*)(bufA_ + SW(la_));               \
            acc[mi] = __builtin_amdgcn_mfma_f32_16x16x32_bf16(av_, bv_, acc[mi], 0, 0, 0); \
        }                                                                 \
    }

    for (int it = 0; it < NSTEPS; it += 2) {
        STEP(it,     qa0, qa1);
        STEP(it + 1, qb0, qb1);
    }
#undef STEP
#undef ISSUE_A
#undef LOAD_B

    // ---- epilogue: bf16 partials (C/D: col=lane&15, row=(lane>>4)*4+reg) ----
    __bf16* outp = partial + (size_t)split * ((size_t)M_DIM * K_DIM);
    const int gk = k0 + w * 16 + (lane & 15);
#pragma unroll
    for (int mi = 0; mi < 16; ++mi) {
        int gm = mi * 16 + (lane >> 4) * 4;
#pragma unroll
        for (int rix = 0; rix < 4; ++rix)
            outp[(size_t)(gm + rix) * K_DIM + gk] = (__bf16)acc[mi][rix];
    }
}

// ---------------- Kernel 2: out = mu2[k] * sum_splits + bias[k] ----------------
__global__ __launch_bounds__(256) void reduce_out(const __bf16* __restrict__ partial,
                                                  const float* __restrict__ mu2,
                                                  const float* __restrict__ bias,
                                                  float* __restrict__ out) {
    int t  = blockIdx.x * 256 + threadIdx.x;
    int k4 = t & 2047;
    int m  = t >> 11;
    size_t base = (size_t)m * K_DIM + (size_t)k4 * 4;
    float4 s; s.x = 0.f; s.y = 0.f; s.z = 0.f; s.w = 0.f;
#pragma unroll
    for (int sp = 0; sp < SPLITN; ++sp) {
        bf16x4 p = *(const bf16x4*)(partial + (size_t)sp * ((size_t)M_DIM * K_DIM) + base);
        s.x += (float)p[0]; s.y += (float)p[1]; s.z += (float)p[2]; s.w += (float)p[3];
    }
    float4 m2 = *(const float4*)(mu2 + (size_t)k4 * 4);
    float4 bi = *(const float4*)(bias + (size_t)k4 * 4);
    float4 o;
    o.x = s.x * m2.x + bi.x;
    o.y = s.y * m2.y + bi.y;
    o.z = s.z * m2.z + bi.z;
    o.w = s.w * m2.w + bi.w;
    *(float4*)(out + base) = o;
}

extern "C" void kernel_launch(void* const* d_in, const int* in_sizes, int n_in,
                              void* d_out, int out_size, void* d_ws, size_t ws_size,
                              hipStream_t stream) {
    const float* x      = (const float*)d_in[0];
    const int*   Wq     = (const int*)d_in[1];
    const float* scales = (const float*)d_in[2];
    const float* zeros  = (const float*)d_in[3];
    const float* mu1    = (const float*)d_in[4];
    const float* mu2    = (const float*)d_in[5];
    const float* bias   = (const float*)d_in[6];
    float* out = (float*)d_out;

    __bf16* xs = (__bf16*)d_ws;
    const size_t xs_bytes = (size_t)M_DIM * N_DIM * sizeof(__bf16);   // 4 MB
    __bf16* partial = (__bf16*)((char*)d_ws + xs_bytes);              // 8 x 4 MB

    (void)hipFuncSetAttribute((const void*)gemm_q,
                              hipFuncAttributeMaxDynamicSharedMemorySize,
                              LDS_TOTAL);

    prep_xs<<<2048, 256, 0, stream>>>(x, mu1, xs);
    gemm_q<<<64 * SPLITN, THREADS, LDS_TOTAL, stream>>>(xs, Wq, scales, zeros, partial);
    reduce_out<<<2048, 256, 0, stream>>>(partial, mu2, bias, out);
}

// Round 8
// 89.505 us; speedup vs baseline: 1.1509x; 1.1509x over previous
//
#include <hip/hip_runtime.h>
#include <hip/hip_bf16.h>

// Problem constants
#define M_DIM 256     // B*T
#define K_DIM 8192
#define N_DIM 8192
#define NGRP  64      // N/128 groups

// Tile config
#define BN 128        // W rows per block
#define BK 32         // n per step
#define THREADS 512   // 8 waves: 2 (m) x 4 (k)
#define SPLITN 8
#define CHUNK  (N_DIM / SPLITN)   // 1024
#define NSTEPS (CHUNK / BK)       // 32
#define NG     (CHUNK >> 7)       // 8 groups per chunk

// LDS: A triple-buffered (global_load_lds) + B double-buffered bf16 + scales
#define ASIZE 16384               // bf16 [256][32]
#define BSIZE 8192                // bf16 [128][32]
#define B_OFF  (3 * ASIZE)        // 49152
#define SL_OFF (B_OFF + 2 * BSIZE)            // 65536
#define LDS_TOTAL (SL_OFF + NG * 128 * 8)     // 73728 (72KB) -> 2 blocks/CU

typedef __bf16 bf16x8 __attribute__((ext_vector_type(8)));
typedef __bf16 bf16x4 __attribute__((ext_vector_type(4)));
typedef float  f32x4  __attribute__((ext_vector_type(4)));

// XOR swizzle (involution): slot bits [6:4] ^= row bits [9:7]. Used for A and B.
#define SW(a) ((a) ^ ((((a) >> 7) & 7) << 4))

#define GLOAD_LDS16(g, l) __builtin_amdgcn_global_load_lds( \
    (const __attribute__((address_space(1))) void*)(g),     \
    (__attribute__((address_space(3))) void*)(l), 16, 0, 0)

// ---------------- Kernel 0: xs[m,n] = bf16(x[m,n] * mu1[n]) ----------------
__global__ __launch_bounds__(256) void prep_xs(const float* __restrict__ x,
                                               const float* __restrict__ mu1,
                                               __bf16* __restrict__ xs) {
    int t  = blockIdx.x * 256 + threadIdx.x;
    int n4 = t & 2047;
    int m  = t >> 11;
    int n  = n4 << 2;
    float4 xv = *(const float4*)(x + (size_t)m * N_DIM + n);
    float4 mv = *(const float4*)(mu1 + n);
    bf16x4 o;
    o[0] = (__bf16)(xv.x * mv.x);
    o[1] = (__bf16)(xv.y * mv.y);
    o[2] = (__bf16)(xv.z * mv.z);
    o[3] = (__bf16)(xv.w * mv.w);
    *(bf16x4*)(xs + (size_t)m * N_DIM + n) = o;
}

// ---------------- Kernel 1: single-barrier-per-step split-K GEMM ----------------
__global__ __launch_bounds__(THREADS, 4)
void gemm_q(const __bf16* __restrict__ xs, const int* __restrict__ Wq,
            const float* __restrict__ scales, const float* __restrict__ zeros,
            __bf16* __restrict__ partial) {
    extern __shared__ __align__(1024) char lds[];

    const int b     = blockIdx.x;      // 512 blocks
    const int split = b & 7;           // XCD-affine split
    const int kidx  = b >> 3;          // 0..63
    const int k0    = kidx * BN;
    const int nbase = split * CHUNK;
    const int gbase = split * NG;

    const int tid  = threadIdx.x;
    const int lane = tid & 63;
    const int w    = tid >> 6;   // 0..7
    const int wm   = w >> 2;     // m half
    const int wn   = w & 3;      // k quarter
    const int start = kidx & (NSTEPS - 1);   // n-rotation

    float* SL = (float*)(lds + SL_OFF);      // [NG][128] x {s, -z*s}

    // ---- stage scales/zeros (once) ----
    {
        int r = tid >> 2, gq = tid & 3;
#pragma unroll
        for (int gg = 0; gg < (NG >> 2); ++gg) {
            int g = (gg << 2) | gq;
            size_t si = (size_t)(k0 + r) * NGRP + gbase + g;
            float s = scales[si];
            float z = zeros[si];
            float2 v; v.x = s; v.y = -z * s;
            *(float2*)&SL[(size_t)((g << 7) + r) * 2] = v;
        }
    }
    // full drain BEFORE pipeline loads so the vmcnt ledger starts at 0
    asm volatile("s_waitcnt vmcnt(0) lgkmcnt(0)" ::: "memory");
    __builtin_amdgcn_s_barrier();

    // ---- A staging via global_load_lds: 2x 1KB chunks per wave ----
    const char* asrc[2];
    int aoff[2];
#pragma unroll
    for (int cc = 0; cc < 2; ++cc) {
        int c   = w * 2 + cc;            // 0..15
        int off = c * 1024 + lane * 16;  // linear LDS dest
        int L   = SW(off);               // inverse-swizzled source element
        aoff[cc] = off;
        asrc[cc] = (const char*)xs + ((size_t)(L >> 6) * N_DIM) * 2 + (L & 63);
    }

    // ---- B staging: lane owns row 16w+(l>>2), 8 codes at col (l&3)*8 ----
    const int brow = w * 16 + (lane >> 2);        // 0..127
    const int bq   = lane & 3;
    const int* bptr0 = Wq + (size_t)(k0 + brow) * N_DIM + bq * 8;
    char* bdst0 = lds + B_OFF + SW(brow * 64 + bq * 16);  // swizzled B write

    // B frag read offsets (swizzled, matches write involution)
    const int rboff0 = SW((wn * 32 + 0  + (lane & 15)) * 64 + (lane >> 4) * 16);
    const int rboff1 = SW((wn * 32 + 16 + (lane & 15)) * 64 + (lane >> 4) * 16);

    // rotating A buffers: pA0 = read this step, pA1 = issue target (step+1)
    char* pA0 = lds;
    char* pA1 = lds + ASIZE;
    char* pA2 = lds + 2 * ASIZE;

#define ISSUE_A(t, pbuf)                                                  \
    {                                                                     \
        int s_ = ((t) + start) & (NSTEPS - 1);                            \
        size_t so_ = (size_t)(nbase + s_ * BK) * 2;                       \
        GLOAD_LDS16(asrc[0] + so_, (pbuf) + aoff[0]);                     \
        GLOAD_LDS16(asrc[1] + so_, (pbuf) + aoff[1]);                     \
    }
#define LOAD_B(t, q0, q1)                                                 \
    {                                                                     \
        int s_ = ((t) + start) & (NSTEPS - 1);                            \
        const int* p_ = bptr0 + (nbase + s_ * BK);                        \
        q0 = *(const int4*)p_;                                            \
        q1 = *(const int4*)(p_ + 4);                                      \
    }

    f32x4 acc[8][2];
#pragma unroll
    for (int i = 0; i < 8; ++i) {
        acc[i][0] = (f32x4){0.f, 0.f, 0.f, 0.f};
        acc[i][1] = (f32x4){0.f, 0.f, 0.f, 0.f};
    }

    int4 qa0, qa1, qb0, qb1;

    // prologue queue: [B0,B0 | A0,A0 | B1,B1]  (6 outstanding)
    LOAD_B(0, qa0, qa1);
    asm volatile("" ::: "memory");
    ISSUE_A(0, pA0);
    asm volatile("" ::: "memory");
    LOAD_B(1, qb0, qb1);

    // STEP (single barrier). Ledger (steady): entry 6 = [B(i),B(i),A(i),A(i),B(i+1),B(i+1)]
    //  W1 drains B(i) codes; issue A(i+1) then B(i+2); W4 drains A(i); barrier; compute.
#define STEP(it, q0c, q1c, W1, W4, DO_A, DO_B)                            \
    {                                                                     \
        asm volatile("s_waitcnt vmcnt(" #W1 ")" ::: "memory");            \
        int scur_ = ((it) + start) & (NSTEPS - 1);                        \
        float2 sz_ = *(float2*)&SL[(size_t)(((scur_ >> 2) << 7) + brow) * 2]; \
        bf16x8 wv_;                                                       \
        wv_[0] = (__bf16)((float)q0c.x * sz_.x + sz_.y);                  \
        wv_[1] = (__bf16)((float)q0c.y * sz_.x + sz_.y);                  \
        wv_[2] = (__bf16)((float)q0c.z * sz_.x + sz_.y);                  \
        wv_[3] = (__bf16)((float)q0c.w * sz_.x + sz_.y);                  \
        wv_[4] = (__bf16)((float)q1c.x * sz_.x + sz_.y);                  \
        wv_[5] = (__bf16)((float)q1c.y * sz_.x + sz_.y);                  \
        wv_[6] = (__bf16)((float)q1c.z * sz_.x + sz_.y);                  \
        wv_[7] = (__bf16)((float)q1c.w * sz_.x + sz_.y);                  \
        *(bf16x8*)(bdst0 + ((it) & 1) * BSIZE) = wv_;                     \
        if (DO_A) { ISSUE_A((it) + 1, pA1); }                             \
        asm volatile("" ::: "memory");                                    \
        if (DO_B) { LOAD_B((it) + 2, q0c, q1c); }                         \
        asm volatile("s_waitcnt vmcnt(" #W4 ") lgkmcnt(0)" ::: "memory"); \
        __builtin_amdgcn_s_barrier();                                     \
        const char* bufA_ = pA0;                                          \
        const char* bufB_ = lds + B_OFF + ((it) & 1) * BSIZE;             \
        bf16x8 bv0_ = *(const bf16x8*)(bufB_ + rboff0);                   \
        bf16x8 bv1_ = *(const bf16x8*)(bufB_ + rboff1);                   \
        __builtin_amdgcn_s_setprio(1);                                    \
        _Pragma("unroll")                                                 \
        for (int mi = 0; mi < 8; ++mi) {                                  \
            int la_ = (wm * 128 + mi * 16 + (lane & 15)) * 64 + (lane >> 4) * 16; \
            bf16x8 av_ = *(const bf16x8*)(bufA_ + SW(la_));               \
            acc[mi][0] = __builtin_amdgcn_mfma_f32_16x16x32_bf16(av_, bv0_, acc[mi][0], 0, 0, 0); \
            acc[mi][1] = __builtin_amdgcn_mfma_f32_16x16x32_bf16(av_, bv1_, acc[mi][1], 0, 0, 0); \
        }                                                                 \
        __builtin_amdgcn_s_setprio(0);                                    \
        { char* t_ = pA0; pA0 = pA1; pA1 = pA2; pA2 = t_; }               \
    }

    // steady iters 0..NSTEPS-3 (unrolled x2), then peeled tail
    for (int it = 0; it < NSTEPS - 2; it += 2) {
        STEP(it,     qa0, qa1, 4, 6, true, true);
        STEP(it + 1, qb0, qb1, 4, 6, true, true);
    }
    STEP(NSTEPS - 2, qa0, qa1, 4, 4, true,  false);
    STEP(NSTEPS - 1, qb0, qb1, 2, 0, false, false);
#undef STEP
#undef ISSUE_A
#undef LOAD_B

    // ---- epilogue: bf16 partials (C/D: col=lane&15, row=(lane>>4)*4+reg) ----
    __bf16* outp = partial + (size_t)split * ((size_t)M_DIM * K_DIM);
#pragma unroll
    for (int mi = 0; mi < 8; ++mi) {
#pragma unroll
        for (int ci = 0; ci < 2; ++ci) {
            int gk = k0 + wn * 32 + ci * 16 + (lane & 15);
            int gm = wm * 128 + mi * 16 + (lane >> 4) * 4;
#pragma unroll
            for (int rix = 0; rix < 4; ++rix)
                outp[(size_t)(gm + rix) * K_DIM + gk] = (__bf16)acc[mi][ci][rix];
        }
    }
}

// ---------------- Kernel 2: out = mu2[k] * sum_splits + bias[k] ----------------
__global__ __launch_bounds__(256) void reduce_out(const __bf16* __restrict__ partial,
                                                  const float* __restrict__ mu2,
                                                  const float* __restrict__ bias,
                                                  float* __restrict__ out) {
    int t  = blockIdx.x * 256 + threadIdx.x;
    int k4 = t & 2047;
    int m  = t >> 11;
    size_t base = (size_t)m * K_DIM + (size_t)k4 * 4;
    float4 s; s.x = 0.f; s.y = 0.f; s.z = 0.f; s.w = 0.f;
#pragma unroll
    for (int sp = 0; sp < SPLITN; ++sp) {
        bf16x4 p = *(const bf16x4*)(partial + (size_t)sp * ((size_t)M_DIM * K_DIM) + base);
        s.x += (float)p[0]; s.y += (float)p[1]; s.z += (float)p[2]; s.w += (float)p[3];
    }
    float4 m2 = *(const float4*)(mu2 + (size_t)k4 * 4);
    float4 bi = *(const float4*)(bias + (size_t)k4 * 4);
    float4 o;
    o.x = s.x * m2.x + bi.x;
    o.y = s.y * m2.y + bi.y;
    o.z = s.z * m2.z + bi.z;
    o.w = s.w * m2.w + bi.w;
    *(float4*)(out + base) = o;
}

extern "C" void kernel_launch(void* const* d_in, const int* in_sizes, int n_in,
                              void* d_out, int out_size, void* d_ws, size_t ws_size,
                              hipStream_t stream) {
    const float* x      = (const float*)d_in[0];
    const int*   Wq     = (const int*)d_in[1];
    const float* scales = (const float*)d_in[2];
    const float* zeros  = (const float*)d_in[3];
    const float* mu1    = (const float*)d_in[4];
    const float* mu2    = (const float*)d_in[5];
    const float* bias   = (const float*)d_in[6];
    float* out = (float*)d_out;

    __bf16* xs = (__bf16*)d_ws;
    const size_t xs_bytes = (size_t)M_DIM * N_DIM * sizeof(__bf16);   // 4 MB
    __bf16* partial = (__bf16*)((char*)d_ws + xs_bytes);              // 8 x 4 MB

    (void)hipFuncSetAttribute((const void*)gemm_q,
                              hipFuncAttributeMaxDynamicSharedMemorySize,
                              LDS_TOTAL);

    prep_xs<<<2048, 256, 0, stream>>>(x, mu1, xs);
    gemm_q<<<64 * SPLITN, THREADS, LDS_TOTAL, stream>>>(xs, Wq, scales, zeros, partial);
    reduce_out<<<2048, 256, 0, stream>>>(partial, mu2, bias, out);
}